// Round 7
// baseline (571.704 us; speedup 1.0000x reference)
//
#include <hip/hip_runtime.h>

#define NB 512
#define KNB 30
#define HID 128
#define NL 3
#define NOUT 400
#define NFF 512

typedef _Float16 f16;
typedef _Float16 f16x8 __attribute__((ext_vector_type(8)));
typedef _Float16 f16x4 __attribute__((ext_vector_type(4)));
typedef float f32x4 __attribute__((ext_vector_type(4)));

#define MFMA16(a, b, c) __builtin_amdgcn_mfma_f32_16x16x32_f16(a, b, c, 0, 0, 0)
#define FLTMIN -3.4028234663852886e38f

// packed weight offsets (in f16 elements)
#define PK_WE   0
#define PK_WQ   16384
#define PK_WK   65536
#define PK_WV   114688
#define PK_WO   163840
#define PK_F1   212992
#define PK_F2   409600
#define PK_WOUT 606208
#define PK_TOTAL 657408

// ---------------- fp32 helper kernels ----------------
__global__ void k_hv(const float* __restrict__ V, const float* __restrict__ Wv,
                     const float* __restrict__ bv, float* __restrict__ hV) {
  int idx = blockIdx.x * 256 + threadIdx.x;
  int row = idx >> 7, c = idx & 127;
  const float* vr = V + row * HID;
  float acc = bv[c];
  for (int i = 0; i < HID; ++i) acc = fmaf(vr[i], Wv[i * HID + c], acc);
  hV[idx] = acc;
}

__global__ void k_tables(const float* __restrict__ hV, const float* __restrict__ WK,
                         const float* __restrict__ WVp, float* __restrict__ tbl) {
  int idx = blockIdx.x * 256 + threadIdx.x;   // 1,572,864
  int c = idx & 127;
  int row = (idx >> 7) & 1023;
  int t = idx >> 17;                 // 0..11
  int l = t >> 2, part = t & 3;
  const float* W;
  if (part == 0)      W = WK  + l * 3 * HID * HID;
  else if (part == 1) W = WK  + l * 3 * HID * HID + HID * HID;
  else if (part == 2) W = WVp + l * 3 * HID * HID;
  else                W = WVp + l * 3 * HID * HID + HID * HID;
  const float* hr = hV + row * HID;
  float acc = 0.f;
  for (int i = 0; i < HID; ++i) acc = fmaf(hr[i], W[i * HID + c], acc);
  tbl[idx] = acc;
}

// ---------------- weight packing: B-fragment order, f16 ----------------
__device__ __forceinline__ void pack_one(const float* W, int N, int r, f16* dst) {
  int j = r & 7, l = (r >> 3) & 63, t = r >> 9;
  int NT = N >> 4;
  int nt = t % NT, ks = t / NT;
  int k = ks * 32 + ((l >> 4) << 3) + j;
  int c = nt * 16 + (l & 15);
  dst[r] = (f16)W[k * N + c];
}

__global__ void k_pack(const float* __restrict__ We, const float* __restrict__ WQ,
                       const float* __restrict__ WK, const float* __restrict__ WV,
                       const float* __restrict__ WO, const float* __restrict__ f1w,
                       const float* __restrict__ f2w, const float* __restrict__ Wout,
                       f16* __restrict__ P) {
  int idx = blockIdx.x * 256 + threadIdx.x;
  if (idx >= PK_TOTAL) return;
  const float* W; int N; int r; f16* dst;
  if (idx < 212992) {
    int s = idx >> 14; r = idx & 16383; N = 128;
    dst = P + (idx - r);
    if (s == 0) W = We;
    else if (s < 4) W = WQ + (s - 1) * 16384;
    else if (s < 7) W = WK + (s - 4) * 49152 + 32768;
    else if (s < 10) W = WV + (s - 7) * 49152 + 32768;
    else W = WO + (s - 10) * 16384;
  } else if (idx < 409600) {
    int t = (idx - 212992) >> 16; r = (idx - 212992) & 65535;
    W = f1w + t * 65536; N = 512; dst = P + 212992 + t * 65536;
  } else if (idx < 606208) {
    int t = (idx - 409600) >> 16; r = (idx - 409600) & 65535;
    W = f2w + t * 65536; N = 128; dst = P + 409600 + t * 65536;
  } else {
    r = idx - 606208; W = Wout; N = 400; dst = P + 606208;
  }
  pack_one(W, N, r, dst);
}

// ---------------- register-resident LayerNorm (16 rows per wave) ----------------
__device__ __forceinline__ void ln_regs(f32x4 res[8], const float* __restrict__ gp,
                                        const float* __restrict__ bp, float mmul,
                                        f16* hEhA, int ln, int g) {
  float s1[4] = {0.f, 0.f, 0.f, 0.f}, s2[4] = {0.f, 0.f, 0.f, 0.f};
#pragma unroll
  for (int nt = 0; nt < 8; ++nt)
#pragma unroll
    for (int i = 0; i < 4; ++i) { float x = res[nt][i]; s1[i] += x; s2[i] += x * x; }
#pragma unroll
  for (int o = 1; o < 16; o <<= 1)
#pragma unroll
    for (int i = 0; i < 4; ++i) { s1[i] += __shfl_xor(s1[i], o); s2[i] += __shfl_xor(s2[i], o); }
  float mu[4], inv[4];
#pragma unroll
  for (int i = 0; i < 4; ++i) {
    mu[i] = s1[i] * (1.f / 128.f);
    float var = fmaf(-s1[i], mu[i], s2[i]) * (1.f / 127.f);
    inv[i] = 1.f / (sqrtf(var + 1e-6f) + 1e-6f);
  }
#pragma unroll
  for (int nt = 0; nt < 8; ++nt) {
    float gl = gp[nt * 16 + ln], bl = bp[nt * 16 + ln];
#pragma unroll
    for (int i = 0; i < 4; ++i) {
      float y = (gl * (res[nt][i] - mu[i]) * inv[i] + bl) * mmul;
      res[nt][i] = y;
      hEhA[(4 * g + i) * 136 + nt * 16 + ln] = (f16)y;
    }
  }
}

__attribute__((amdgpu_flat_work_group_size(128, 128), amdgpu_waves_per_eu(2, 2)))
__global__ void k_main(
    const float* __restrict__ E, const int* __restrict__ Eix, const float* __restrict__ xm,
    const float* __restrict__ be,
    const float* __restrict__ l1g, const float* __restrict__ l1b,
    const float* __restrict__ l2g, const float* __restrict__ l2b,
    const float* __restrict__ f1b, const float* __restrict__ f2b,
    const float* __restrict__ bout,
    const f16* __restrict__ P, const float* __restrict__ tbl,
    float* __restrict__ gOUT) {
  // LDS: Kh [32][136] 8704 | Vt [128][40] 10240 | ma 128 | 2x hEh [16][136] 4352
  //      | 2x pool (Qh [16][136] 4352 + ath [16][40] 1280 = 5632)  => 39040 B
  __shared__ __align__(16) char SM[39040];
  f16* Kh = (f16*)SM;
  f16* Vt = (f16*)(SM + 8704);
  float* ma = (float*)(SM + 18944);

  const int tid = threadIdx.x;
  const int w = tid >> 6, lane = tid & 63, ln = lane & 15, g = lane >> 4;
  f16* hEhA = (f16*)(SM + 19072 + w * 4352);   // [16][136] private
  f16* Qh   = (f16*)(SM + 27776 + w * 5632);   // [16][136] private
  f16* ath  = Qh + 2176;                        // [16][40] private
  f16* hidc = Qh;                               // FF chunk, aliases Qh

  const int bid = blockIdx.x;
  const int b = bid >> 9, n = bid & (NB - 1);
  const int rb = w * 16;
  const int ebase = (b * NB + n) * KNB;
  const float mrow = xm[b * NB + n];

  int rr[4], er[4];
#pragma unroll
  for (int i = 0; i < 4; ++i) {
    rr[i] = rb + 4 * g + i;
    er[i] = (rr[i] < KNB) ? Eix[ebase + rr[i]] : 0;
  }
  const int e0 = Eix[ebase];

  if (w == 0 && lane < 32)
    ma[lane] = (lane < KNB) ? mrow * xm[b * NB + Eix[ebase + lane]] : 0.f;

  // E tile -> hEhA f16 (own 16 rows; rows >= 30 zeroed)
  for (int x = lane; x < 512; x += 64) {
    int lr = x >> 5, c4 = (x & 31) << 2;
    int r = rb + lr;
    f16x4 h4 = {};
    if (r < KNB) {
      float4 e4 = *(const float4*)(E + (size_t)ebase * HID + (size_t)r * HID + c4);
      h4[0] = (f16)e4.x; h4[1] = (f16)e4.y; h4[2] = (f16)e4.z; h4[3] = (f16)e4.w;
    }
    *(f16x4*)&hEhA[lr * 136 + c4] = h4;
  }

  f32x4 res[8];

  // ---- init: hE = E @ We + be ----
  {
    f16x8 af[4];
#pragma unroll
    for (int ks = 0; ks < 4; ++ks)
      af[ks] = *(const f16x8*)&hEhA[ln * 136 + ks * 32 + g * 8];
    f32x4 acc[8] = {};
    const f16x8* PB = (const f16x8*)(P + PK_WE);
#pragma unroll
    for (int ks = 0; ks < 4; ++ks)
#pragma unroll
      for (int nt = 0; nt < 8; ++nt)
        acc[nt] = MFMA16(af[ks], PB[(ks * 8 + nt) * 64 + lane], acc[nt]);
#pragma unroll
    for (int nt = 0; nt < 8; ++nt) {
      float bev = be[nt * 16 + ln];
#pragma unroll
      for (int i = 0; i < 4; ++i) res[nt][i] = acc[nt][i] + bev;
    }
#pragma unroll
    for (int nt = 0; nt < 8; ++nt)
#pragma unroll
      for (int i = 0; i < 4; ++i)
        hEhA[(4 * g + i) * 136 + nt * 16 + ln] = (f16)res[nt][i];
  }
  __syncthreads();   // ma visible

  float mam[4];
#pragma unroll
  for (int i = 0; i < 4; ++i) mam[i] = ma[rr[i] & 31];
  const float mk0 = ma[ln], mk1 = ma[16 + ln];

  // ---------------- layers ----------------
  for (int l = 0; l < NL; ++l) {
    const f16x8* PQ = (const f16x8*)(P + PK_WQ + l * 16384);
    const f16x8* PKk = (const f16x8*)(P + PK_WK + l * 16384);
    const f16x8* PV = (const f16x8*)(P + PK_WV + l * 16384);
    const f16x8* PO = (const f16x8*)(P + PK_WO + l * 16384);
    const f16x8* P1 = (const f16x8*)(P + PK_F1 + l * 65536);
    const f16x8* P2 = (const f16x8*)(P + PK_F2 + l * 65536);
    const float* Ki = tbl + (size_t)(l * 4 + 0) * (2 * NB * HID) + (size_t)b * NB * HID;
    const float* Kj = tbl + (size_t)(l * 4 + 1) * (2 * NB * HID) + (size_t)b * NB * HID;
    const float* Vi = tbl + (size_t)(l * 4 + 2) * (2 * NB * HID) + (size_t)b * NB * HID;
    const float* Vj = tbl + (size_t)(l * 4 + 3) * (2 * NB * HID) + (size_t)b * NB * HID;

    f16x8 af[4];
#pragma unroll
    for (int ks = 0; ks < 4; ++ks)
      af[ks] = *(const f16x8*)&hEhA[ln * 136 + ks * 32 + g * 8];

    // Q (no gathers)
    {
      f32x4 acc[8] = {};
#pragma unroll
      for (int ks = 0; ks < 4; ++ks)
#pragma unroll
        for (int nt = 0; nt < 8; ++nt)
          acc[nt] = MFMA16(af[ks], PQ[(ks * 8 + nt) * 64 + lane], acc[nt]);
#pragma unroll
      for (int nt = 0; nt < 8; ++nt)
#pragma unroll
        for (int i = 0; i < 4; ++i)
          Qh[(4 * g + i) * 136 + nt * 16 + ln] = (f16)acc[nt][i];
    }
    // K: two half-phases of 4 nt; prefetch 20 node-part floats per half
#pragma unroll
    for (int hf = 0; hf < 2; ++hf) {
      float ki[4], kj0[4], kj1[4], kj2[4], kj3[4];
#pragma unroll
      for (int q = 0; q < 4; ++q) {
        int c = (hf * 4 + q) * 16 + ln;
        ki[q]  = Ki[e0 * HID + c];
        kj0[q] = Kj[er[0] * HID + c];
        kj1[q] = Kj[er[1] * HID + c];
        kj2[q] = Kj[er[2] * HID + c];
        kj3[q] = Kj[er[3] * HID + c];
      }
      f32x4 acc[4] = {};
#pragma unroll
      for (int ks = 0; ks < 4; ++ks)
#pragma unroll
        for (int q = 0; q < 4; ++q)
          acc[q] = MFMA16(af[ks], PKk[(ks * 8 + hf * 4 + q) * 64 + lane], acc[q]);
#pragma unroll
      for (int q = 0; q < 4; ++q) {
        int c = (hf * 4 + q) * 16 + ln;
        Kh[(rb + 4 * g + 0) * 136 + c] = (f16)(acc[q][0] + ki[q] + kj0[q]);
        Kh[(rb + 4 * g + 1) * 136 + c] = (f16)(acc[q][1] + ki[q] + kj1[q]);
        Kh[(rb + 4 * g + 2) * 136 + c] = (f16)(acc[q][2] + ki[q] + kj2[q]);
        Kh[(rb + 4 * g + 3) * 136 + c] = (f16)(acc[q][3] + ki[q] + kj3[q]);
      }
    }
    // V: two half-phases, transposed stores
#pragma unroll
    for (int hf = 0; hf < 2; ++hf) {
      float vi[4], vj0[4], vj1[4], vj2[4], vj3[4];
#pragma unroll
      for (int q = 0; q < 4; ++q) {
        int c = (hf * 4 + q) * 16 + ln;
        vi[q]  = Vi[e0 * HID + c];
        vj0[q] = Vj[er[0] * HID + c];
        vj1[q] = Vj[er[1] * HID + c];
        vj2[q] = Vj[er[2] * HID + c];
        vj3[q] = Vj[er[3] * HID + c];
      }
      f32x4 acc[4] = {};
#pragma unroll
      for (int ks = 0; ks < 4; ++ks)
#pragma unroll
        for (int q = 0; q < 4; ++q)
          acc[q] = MFMA16(af[ks], PV[(ks * 8 + hf * 4 + q) * 64 + lane], acc[q]);
#pragma unroll
      for (int q = 0; q < 4; ++q) {
        int c = (hf * 4 + q) * 16 + ln;
        Vt[c * 40 + rb + 4 * g + 0] = (f16)(acc[q][0] + vi[q] + vj0[q]);
        Vt[c * 40 + rb + 4 * g + 1] = (f16)(acc[q][1] + vi[q] + vj1[q]);
        Vt[c * 40 + rb + 4 * g + 2] = (f16)(acc[q][2] + vi[q] + vj2[q]);
        Vt[c * 40 + rb + 4 * g + 3] = (f16)(acc[q][3] + vi[q] + vj3[q]);
      }
    }
    __syncthreads();   // B1: Kh/Vt complete

    // ---- attention (own 16 q-rows, all 4 heads) ----
    const float scale = 0.17677669529663687f;
#pragma unroll
    for (int h = 0; h < 4; ++h) {
      f16x8 aq = *(const f16x8*)&Qh[ln * 136 + h * 32 + g * 8];
      f16x8 bk0 = *(const f16x8*)&Kh[ln * 136 + h * 32 + g * 8];
      f16x8 bk1 = *(const f16x8*)&Kh[(16 + ln) * 136 + h * 32 + g * 8];
      f32x4 s0 = {}, s1v = {};
      s0 = MFMA16(aq, bk0, s0);
      s1v = MFMA16(aq, bk1, s1v);
      float a0[4], a1[4];
#pragma unroll
      for (int i = 0; i < 4; ++i) {
        float mq = mam[i];
        float p0 = mq * mk0, p1 = mq * mk1;
        float v0 = (p0 > 0.f) ? s0[i] * scale : FLTMIN;
        float v1 = (p1 > 0.f) ? s1v[i] * scale : FLTMIN;
        float mx = fmaxf(v0, v1);
        mx = fmaxf(mx, __shfl_xor(mx, 1));
        mx = fmaxf(mx, __shfl_xor(mx, 2));
        mx = fmaxf(mx, __shfl_xor(mx, 4));
        mx = fmaxf(mx, __shfl_xor(mx, 8));
        float e0v = __expf(v0 - mx), e1v = __expf(v1 - mx);
        float sm = e0v + e1v;
        sm += __shfl_xor(sm, 1); sm += __shfl_xor(sm, 2);
        sm += __shfl_xor(sm, 4); sm += __shfl_xor(sm, 8);
        float iv = 1.f / sm;
        a0[i] = e0v * iv * p0;
        a1[i] = e1v * iv * p1;
      }
#pragma unroll
      for (int i = 0; i < 4; ++i) {
        ath[(4 * g + i) * 40 + ln] = (f16)a0[i];
        ath[(4 * g + i) * 40 + 16 + ln] = (f16)a1[i];
      }
      f16x8 pa = *(const f16x8*)&ath[ln * 40 + g * 8];
      f16x8 bv0 = *(const f16x8*)&Vt[(h * 32 + ln) * 40 + g * 8];
      f16x8 bv1 = *(const f16x8*)&Vt[(h * 32 + 16 + ln) * 40 + g * 8];
      f32x4 u0 = {}, u1 = {};
      u0 = MFMA16(pa, bv0, u0);
      u1 = MFMA16(pa, bv1, u1);
#pragma unroll
      for (int i = 0; i < 4; ++i) {
        hEhA[(4 * g + i) * 136 + h * 32 + ln] = (f16)u0[i];
        hEhA[(4 * g + i) * 136 + h * 32 + 16 + ln] = (f16)u1[i];
      }
    }
    __syncthreads();   // B2: Kh/Vt reads done (safe to overwrite next layer)

    // ---- WO: res += upd @ wo ----
    {
      f16x8 au[4];
#pragma unroll
      for (int ks = 0; ks < 4; ++ks)
        au[ks] = *(const f16x8*)&hEhA[ln * 136 + ks * 32 + g * 8];
      f32x4 acc[8] = {};
#pragma unroll
      for (int ks = 0; ks < 4; ++ks)
#pragma unroll
        for (int nt = 0; nt < 8; ++nt)
          acc[nt] = MFMA16(au[ks], PO[(ks * 8 + nt) * 64 + lane], acc[nt]);
#pragma unroll
      for (int nt = 0; nt < 8; ++nt)
#pragma unroll
        for (int i = 0; i < 4; ++i) res[nt][i] += acc[nt][i];
    }
    ln_regs(res, l1g + l * HID, l1b + l * HID, 1.f, hEhA, ln, g);

    // ---- FF (4 chunks of 128 hidden; each chunk in 2 halves of 4 nt) ----
    {
      f16x8 aff[4];
#pragma unroll
      for (int ks = 0; ks < 4; ++ks)
        aff[ks] = *(const f16x8*)&hEhA[ln * 136 + ks * 32 + g * 8];
      f32x4 ff[8] = {};
      const float* b1 = f1b + l * NFF;
#pragma unroll
      for (int ch = 0; ch < 4; ++ch) {
#pragma unroll
        for (int hf = 0; hf < 2; ++hf) {
          f32x4 h1[4] = {};
#pragma unroll
          for (int ks = 0; ks < 4; ++ks)
#pragma unroll
            for (int q = 0; q < 4; ++q)
              h1[q] = MFMA16(aff[ks], P1[(ks * 32 + ch * 8 + hf * 4 + q) * 64 + lane], h1[q]);
#pragma unroll
          for (int q = 0; q < 4; ++q) {
            int nt = hf * 4 + q;
            float b1v = b1[ch * 128 + nt * 16 + ln];
#pragma unroll
            for (int i = 0; i < 4; ++i)
              hidc[(4 * g + i) * 136 + nt * 16 + ln] = (f16)fmaxf(h1[q][i] + b1v, 0.f);
          }
        }
        f16x8 ah[4];
#pragma unroll
        for (int k2 = 0; k2 < 4; ++k2)
          ah[k2] = *(const f16x8*)&hidc[ln * 136 + k2 * 32 + g * 8];
#pragma unroll
        for (int k2 = 0; k2 < 4; ++k2)
#pragma unroll
          for (int nt = 0; nt < 8; ++nt)
            ff[nt] = MFMA16(ah[k2], P2[((ch * 4 + k2) * 8 + nt) * 64 + lane], ff[nt]);
      }
      const float* b2 = f2b + l * HID;
#pragma unroll
      for (int nt = 0; nt < 8; ++nt) {
        float b2v = b2[nt * 16 + ln];
#pragma unroll
        for (int i = 0; i < 4; ++i) res[nt][i] += ff[nt][i] + b2v;
      }
    }
    ln_regs(res, l2g + l * HID, l2b + l * HID, mrow, hEhA, ln, g);
  }

  // ---- h_out = hEh @ Wout + bout ----
  {
    float* gO = gOUT + (size_t)ebase * NOUT;
    f16x8 af[4];
#pragma unroll
    for (int ks = 0; ks < 4; ++ks)
      af[ks] = *(const f16x8*)&hEhA[ln * 136 + ks * 32 + g * 8];
    const f16x8* PW = (const f16x8*)(P + PK_WOUT);
#pragma unroll 5
    for (int nt = 0; nt < 25; ++nt) {
      f32x4 acc = {};
#pragma unroll
      for (int ks = 0; ks < 4; ++ks)
        acc = MFMA16(af[ks], PW[(ks * 25 + nt) * 64 + lane], acc);
      int c = nt * 16 + ln;
      float bo = bout[c];
#pragma unroll
      for (int i = 0; i < 4; ++i)
        if (rr[i] < KNB) gO[(size_t)rr[i] * NOUT + c] = acc[i] + bo;
    }
  }
}

// ---- merge_duplicate_edges ----
__global__ void k_clearT(int* __restrict__ T) {
  int i = blockIdx.x * 256 + threadIdx.x;
  if (i < 2 * NB * NB) T[i] = 0;
}
__global__ void k_buildT(const int* __restrict__ Eix, int* __restrict__ T) {
  int idx = blockIdx.x * 256 + threadIdx.x;
  if (idx < 2 * NB * KNB) {
    int b = idx / (NB * KNB);
    int rem = idx % (NB * KNB);
    int i = rem / KNB, k = rem % KNB;
    int j = Eix[idx];
    atomicMax(&T[(b * NB + i) * NB + j], k + 1);
  }
}
__global__ void k_merge(const float* __restrict__ HO, const int* __restrict__ Eix,
                        const int* __restrict__ T, float* __restrict__ out) {
  int gid = blockIdx.x * 256 + threadIdx.x;
  if (gid >= 2 * NB * KNB * (NOUT / 4)) return;
  int c4 = gid % (NOUT / 4);
  int bnk = gid / (NOUT / 4);
  int b = bnk / (NB * KNB);
  int n = (bnk / KNB) % NB;
  int j = Eix[bnk];
  int kp = T[(b * NB + j) * NB + n];
  float4 a = ((const float4*)HO)[(size_t)bnk * (NOUT / 4) + c4];
  float4 rv = make_float4(0.f, 0.f, 0.f, 0.f);
  if (kp > 0) rv = ((const float4*)HO)[(size_t)((b * NB + j) * KNB + (kp - 1)) * (NOUT / 4) + c4];
  ((float4*)out)[gid] = make_float4(0.5f * (a.x + rv.x), 0.5f * (a.y + rv.y),
                                    0.5f * (a.z + rv.z), 0.5f * (a.w + rv.w));
}

extern "C" void kernel_launch(void* const* d_in, const int* in_sizes, int n_in,
                              void* d_out, int out_size, void* d_ws, size_t ws_size,
                              hipStream_t stream) {
  const float* V   = (const float*)d_in[0];
  const float* E   = (const float*)d_in[1];
  const float* xmk = (const float*)d_in[2];
  const int*   Eix = (const int*)d_in[3];
  const float* Wv  = (const float*)d_in[4];
  const float* bv  = (const float*)d_in[5];
  const float* We  = (const float*)d_in[6];
  const float* be  = (const float*)d_in[7];
  const float* WQ  = (const float*)d_in[8];
  const float* WK  = (const float*)d_in[9];
  const float* WVp = (const float*)d_in[10];
  const float* WO  = (const float*)d_in[11];
  const float* l1g = (const float*)d_in[12];
  const float* l1b = (const float*)d_in[13];
  const float* l2g = (const float*)d_in[14];
  const float* l2b = (const float*)d_in[15];
  const float* f1w = (const float*)d_in[16];
  const float* f1b = (const float*)d_in[17];
  const float* f2w = (const float*)d_in[18];
  const float* f2b = (const float*)d_in[19];
  const float* Wou = (const float*)d_in[20];
  const float* bou = (const float*)d_in[21];

  // ws (floats): HO 12,288,000 | tbl 1,572,864 | hV 131,072 | P (f16) 657,408
  // T (2MB) aliases tbl (tbl dead after k_main).
  float* HO  = (float*)d_ws;
  float* tbl = HO + 12288000ull;
  float* hV  = tbl + 1572864ull;
  f16*   P   = (f16*)(hV + 131072ull);
  int*   T   = (int*)tbl;

  k_hv<<<512, 256, 0, stream>>>(V, Wv, bv, hV);
  k_tables<<<6144, 256, 0, stream>>>(hV, WK, WVp, tbl);
  k_pack<<<2568, 256, 0, stream>>>(We, WQ, WK, WVp, WO, f1w, f2w, Wou, P);
  k_main<<<1024, 128, 0, stream>>>(E, Eix, xmk, be, l1g, l1b, l2g, l2b,
                                   f1b, f2b, bou, P, tbl, HO);
  k_clearT<<<2048, 256, 0, stream>>>(T);
  k_buildT<<<120, 256, 0, stream>>>(Eix, T);
  k_merge<<<12000, 256, 0, stream>>>(HO, Eix, T, (float*)d_out);
}

// Round 8
// 433.860 us; speedup vs baseline: 1.3177x; 1.3177x over previous
//
#include <hip/hip_runtime.h>

#define NB 512
#define KNB 30
#define HID 128
#define NL 3
#define NOUT 400
#define NFF 512

typedef _Float16 f16;
typedef _Float16 f16x8 __attribute__((ext_vector_type(8)));
typedef _Float16 f16x4 __attribute__((ext_vector_type(4)));
typedef float f32x4 __attribute__((ext_vector_type(4)));

#define MFMA16(a, b, c) __builtin_amdgcn_mfma_f32_16x16x32_f16(a, b, c, 0, 0, 0)
#define FLTMIN -3.4028234663852886e38f

// packed weight offsets (in f16 elements)
#define PK_WE   0
#define PK_WQ   16384
#define PK_WK   65536
#define PK_WV   114688
#define PK_WO   163840
#define PK_F1   212992
#define PK_F2   409600
#define PK_WOUT 606208
#define PK_TOTAL 657408

// ---------------- h_V = V @ Wv + bv ----------------
__global__ void k_hv(const float* __restrict__ V, const float* __restrict__ Wv,
                     const float* __restrict__ bv, float* __restrict__ hV) {
  int idx = blockIdx.x * 256 + threadIdx.x;
  int row = idx >> 7, c = idx & 127;
  const float* vr = V + row * HID;
  float acc = bv[c];
  for (int i = 0; i < HID; ++i) acc = fmaf(vr[i], Wv[i * HID + c], acc);
  hV[idx] = acc;
}

__device__ __forceinline__ void pack_one(const float* W, int N, int r, f16* dst) {
  int j = r & 7, l = (r >> 3) & 63, t = r >> 9;
  int NT = N >> 4;
  int nt = t % NT, ks = t / NT;
  int k = ks * 32 + ((l >> 4) << 3) + j;
  int c = nt * 16 + (l & 15);
  dst[r] = (f16)W[k * N + c];
}

// ---------------- fused prep: node tables + weight pack + clear T ----------------
__global__ void k_prep(const float* __restrict__ hV, const float* __restrict__ WK,
                       const float* __restrict__ WVp, float* __restrict__ tbl,
                       const float* __restrict__ We, const float* __restrict__ WQ,
                       const float* __restrict__ WO, const float* __restrict__ f1w,
                       const float* __restrict__ f2w, const float* __restrict__ Wout,
                       f16* __restrict__ P, int* __restrict__ T) {
  int blk = blockIdx.x, tid = threadIdx.x;
  if (blk < 6144) {
    int idx = blk * 256 + tid;        // 1,572,864 table entries
    int c = idx & 127;
    int row = (idx >> 7) & 1023;
    int t = idx >> 17;
    int l = t >> 2, part = t & 3;
    const float* W;
    if (part == 0)      W = WK  + l * 3 * HID * HID;
    else if (part == 1) W = WK  + l * 3 * HID * HID + HID * HID;
    else if (part == 2) W = WVp + l * 3 * HID * HID;
    else                W = WVp + l * 3 * HID * HID + HID * HID;
    const float* hr = hV + row * HID;
    float acc = 0.f;
    for (int i = 0; i < HID; ++i) acc = fmaf(hr[i], W[i * HID + c], acc);
    tbl[idx] = acc;
  } else if (blk < 6144 + 2568) {
    int idx = (blk - 6144) * 256 + tid;
    if (idx >= PK_TOTAL) return;
    const float* W; int N; int r; f16* dst;
    if (idx < 212992) {
      int s = idx >> 14; r = idx & 16383; N = 128;
      dst = P + (idx - r);
      if (s == 0) W = We;
      else if (s < 4) W = WQ + (s - 1) * 16384;
      else if (s < 7) W = WK + (s - 4) * 49152 + 32768;
      else if (s < 10) W = WVp + (s - 7) * 49152 + 32768;
      else W = WO + (s - 10) * 16384;
    } else if (idx < 409600) {
      int t = (idx - 212992) >> 16; r = (idx - 212992) & 65535;
      W = f1w + t * 65536; N = 512; dst = P + 212992 + t * 65536;
    } else if (idx < 606208) {
      int t = (idx - 409600) >> 16; r = (idx - 409600) & 65535;
      W = f2w + t * 65536; N = 128; dst = P + 409600 + t * 65536;
    } else {
      r = idx - 606208; W = Wout; N = 400; dst = P + 606208;
    }
    pack_one(W, N, r, dst);
  } else {
    int i = (blk - 8712) * 256 + tid;
    if (i < 2 * NB * NB) T[i] = 0;
  }
}

// ---------------- GEMM piece: 2 m-tiles x 2 n-tiles, K=128 ----------------
__device__ __forceinline__ void mfma_block8(const f16* Ab, int astr, const f16x8* B,
                                            int nt0, int nt1, f32x4 acc[2][2],
                                            int ln, int g, int lane) {
  f16x8 af[2][4];
#pragma unroll
  for (int mt = 0; mt < 2; ++mt)
#pragma unroll
    for (int ks = 0; ks < 4; ++ks)
      af[mt][ks] = *(const f16x8*)&Ab[(mt * 16 + ln) * astr + ks * 32 + g * 8];
#pragma unroll
  for (int ks = 0; ks < 4; ++ks) {
    f16x8 b0 = B[(ks * 8 + nt0) * 64 + lane];
    f16x8 b1 = B[(ks * 8 + nt1) * 64 + lane];
#pragma unroll
    for (int mt = 0; mt < 2; ++mt) {
      acc[mt][0] = MFMA16(af[mt][ks], b0, acc[mt][0]);
      acc[mt][1] = MFMA16(af[mt][ks], b1, acc[mt][1]);
    }
  }
}

__device__ __forceinline__ void layer_norm_cvt(float (*hEp)[132], f16* hEhp,
                                               const float* __restrict__ gg,
                                               const float* __restrict__ bb,
                                               float mmul, int tid) {
  int r = tid >> 3, g8 = tid & 7;
  if (r < KNB) {
    float x[16]; float s1 = 0.f, s2 = 0.f;
    int cb = g8 * 16;
#pragma unroll
    for (int m = 0; m < 16; ++m) { x[m] = hEp[r][cb + m]; s1 += x[m]; s2 += x[m] * x[m]; }
#pragma unroll
    for (int o = 1; o < 8; o <<= 1) { s1 += __shfl_xor(s1, o); s2 += __shfl_xor(s2, o); }
    float mu = s1 * (1.f / 128.f);
    float var = fmaf(-s1, mu, s2) * (1.f / 127.f);
    float inv = 1.f / (sqrtf(var + 1e-6f) + 1e-6f);
    f16x8 h0, h1;
#pragma unroll
    for (int m = 0; m < 16; ++m) {
      int c = cb + m;
      float y = (gg[c] * (x[m] - mu) * inv + bb[c]) * mmul;
      hEp[r][c] = y;
      if (m < 8) h0[m] = (f16)y; else h1[m - 8] = (f16)y;
    }
    *(f16x8*)&hEhp[r * 136 + cb] = h0;
    *(f16x8*)&hEhp[r * 136 + cb + 8] = h1;
  }
}

__launch_bounds__(256, 3)
__global__ void k_main(
    const float* __restrict__ E, const int* __restrict__ Eix, const float* __restrict__ xm,
    const float* __restrict__ be,
    const float* __restrict__ l1g, const float* __restrict__ l1b,
    const float* __restrict__ l2g, const float* __restrict__ l2b,
    const float* __restrict__ f1b, const float* __restrict__ f2b,
    const float* __restrict__ bout,
    const f16* __restrict__ P, const float* __restrict__ tbl,
    float* __restrict__ gOUT) {
  // LDS 53,504 B -> 3 blocks/CU:
  // hE fp32[32][132] | hEh f16[32][136] | Qh | Kh | Vt f16[128][40] | ma | eidx
  // attn probs alias Kh (after logits); FF hid [32][264] aliases Qh+Kh.
  __shared__ __align__(16) char SM[53504];
  float (*hE)[132] = (float(*)[132])SM;
  f16* hEh = (f16*)(SM + 16896);
  f16* Qh  = (f16*)(SM + 25600);
  f16* Kh  = (f16*)(SM + 34304);
  f16* Vt  = (f16*)(SM + 43008);
  float* ma = (float*)(SM + 53248);
  int* eidx = (int*)(SM + 53376);
  f16* hid = Qh;                      // [32][264] FF-phase alias

  const int tid = threadIdx.x;
  const int wv = tid >> 6, lane = tid & 63, ln = lane & 15, g = lane >> 4;
  const int bid = blockIdx.x;
  const int b = bid >> 9, n = bid & (NB - 1);
  const int ebase = (b * NB + n) * KNB;

  // zero hEh..Vt (36,352 B)
  {
    float4 z = make_float4(0.f, 0.f, 0.f, 0.f);
    float4* p = (float4*)(SM + 16896);
    for (int x = tid; x < 2272; x += 256) p[x] = z;
  }
  if (tid < 32) {
    int e = (tid < KNB) ? Eix[ebase + tid] : 0;
    eidx[tid] = e;
    float mr = xm[b * NB + n];
    ma[tid] = (tid < KNB) ? mr * xm[b * NB + e] : 0.f;
  }
  __syncthreads();
  // E tile -> hEh f16 (rows < 30; rows 30/31 stay zero)
  {
    const float4* Eg = (const float4*)(E + (size_t)ebase * HID);
    for (int x = tid; x < 960; x += 256) {
      float4 e4 = Eg[x];
      int r = x >> 5, c = (x & 31) << 2;
      f16x4 h; h[0] = (f16)e4.x; h[1] = (f16)e4.y; h[2] = (f16)e4.z; h[3] = (f16)e4.w;
      *(f16x4*)&hEh[r * 136 + c] = h;
    }
  }
  const float mrow = xm[b * NB + n];
  __syncthreads();

  // ---- init: hE = E @ We + be ----
  {
    f32x4 acc[2][2] = {};
    mfma_block8(hEh, 136, (const f16x8*)(P + PK_WE), wv, wv + 4, acc, ln, g, lane);
    __syncthreads();   // drain a-frag reads before overwriting hEh
#pragma unroll
    for (int nts = 0; nts < 2; ++nts) {
      int c = (wv + nts * 4) * 16 + ln;
      float bev = be[c];
#pragma unroll
      for (int mt = 0; mt < 2; ++mt)
#pragma unroll
        for (int i = 0; i < 4; ++i) {
          int r = mt * 16 + 4 * g + i;
          if (r < KNB) {
            float v = acc[mt][nts][i] + bev;
            hE[r][c] = v;
            hEh[r * 136 + c] = (f16)v;
          }
        }
    }
  }
  __syncthreads();

  // ---------------- layers ----------------
  for (int l = 0; l < NL; ++l) {
    const f16x8* PQ = (const f16x8*)(P + PK_WQ + l * 16384);
    const f16x8* PKk = (const f16x8*)(P + PK_WK + l * 16384);
    const f16x8* PV = (const f16x8*)(P + PK_WV + l * 16384);
    const f16x8* PO = (const f16x8*)(P + PK_WO + l * 16384);
    const f16x8* P1 = (const f16x8*)(P + PK_F1 + l * 65536);
    const f16x8* P2 = (const f16x8*)(P + PK_F2 + l * 65536);
    const float* Ki = tbl + (size_t)(l * 4 + 0) * (2 * NB * HID) + (size_t)b * NB * HID;
    const float* Kj = tbl + (size_t)(l * 4 + 1) * (2 * NB * HID) + (size_t)b * NB * HID;
    const float* Vi = tbl + (size_t)(l * 4 + 2) * (2 * NB * HID) + (size_t)b * NB * HID;
    const float* Vj = tbl + (size_t)(l * 4 + 3) * (2 * NB * HID) + (size_t)b * NB * HID;

    // ---- QKV projections (gather prefetch + 3x mfma_block8; proven r3 pattern) ----
    {
      int e0v = eidx[0];
      int er[2][4];
#pragma unroll
      for (int mt = 0; mt < 2; ++mt)
#pragma unroll
        for (int i = 0; i < 4; ++i) er[mt][i] = eidx[mt * 16 + 4 * g + i];
      float kib[2], vib[2], kjv[2][2][4], vjv[2][2][4];
#pragma unroll
      for (int nts = 0; nts < 2; ++nts) {
        int c = (wv + nts * 4) * 16 + ln;
        kib[nts] = Ki[e0v * 128 + c];
        vib[nts] = Vi[e0v * 128 + c];
#pragma unroll
        for (int mt = 0; mt < 2; ++mt)
#pragma unroll
          for (int i = 0; i < 4; ++i) {
            kjv[nts][mt][i] = Kj[er[mt][i] * 128 + c];
            vjv[nts][mt][i] = Vj[er[mt][i] * 128 + c];
          }
      }
      f32x4 qa[2][2] = {}, kk[2][2] = {}, va[2][2] = {};
      mfma_block8(hEh, 136, PQ, wv, wv + 4, qa, ln, g, lane);
      mfma_block8(hEh, 136, PKk, wv, wv + 4, kk, ln, g, lane);
      mfma_block8(hEh, 136, PV, wv, wv + 4, va, ln, g, lane);
#pragma unroll
      for (int nts = 0; nts < 2; ++nts) {
        int c = (wv + nts * 4) * 16 + ln;
#pragma unroll
        for (int mt = 0; mt < 2; ++mt)
#pragma unroll
          for (int i = 0; i < 4; ++i) {
            int r = mt * 16 + 4 * g + i;
            Qh[r * 136 + c] = (f16)qa[mt][nts][i];
            Kh[r * 136 + c] = (f16)(kk[mt][nts][i] + kib[nts] + kjv[nts][mt][i]);
            Vt[c * 40 + r]  = (f16)(va[mt][nts][i] + vib[nts] + vjv[nts][mt][i]);
          }
      }
    }
    __syncthreads();   // B1: Qh/Kh/Vt complete

    // ---- attention: wave = head; logits in regs; probs into dead Kh region ----
    {
      const int h = wv;
      const float scale = 0.17677669529663687f;
      f16x8 aq[2], bk[2];
#pragma unroll
      for (int mt = 0; mt < 2; ++mt)
        aq[mt] = *(const f16x8*)&Qh[(mt * 16 + ln) * 136 + h * 32 + g * 8];
#pragma unroll
      for (int nt = 0; nt < 2; ++nt)
        bk[nt] = *(const f16x8*)&Kh[(nt * 16 + ln) * 136 + h * 32 + g * 8];
      f32x4 s[2][2] = {};
#pragma unroll
      for (int mt = 0; mt < 2; ++mt)
#pragma unroll
        for (int nt = 0; nt < 2; ++nt) s[mt][nt] = MFMA16(aq[mt], bk[nt], s[mt][nt]);
      __syncthreads();   // B1.5: all Qh/Kh reads complete -> Kh reusable
      f16* Ph = Kh + h * 1024;   // [32][32] f16 per head
      float mk0 = ma[ln], mk1 = ma[16 + ln];
#pragma unroll
      for (int mt = 0; mt < 2; ++mt) {
#pragma unroll
        for (int i = 0; i < 4; ++i) {
          int q = mt * 16 + 4 * g + i;
          float mq = ma[q];
          float p0 = mq * mk0, p1 = mq * mk1;
          float v0 = (p0 > 0.f) ? s[mt][0][i] * scale : FLTMIN;
          float v1 = (p1 > 0.f) ? s[mt][1][i] * scale : FLTMIN;
          float mx = fmaxf(v0, v1);
          mx = fmaxf(mx, __shfl_xor(mx, 1));
          mx = fmaxf(mx, __shfl_xor(mx, 2));
          mx = fmaxf(mx, __shfl_xor(mx, 4));
          mx = fmaxf(mx, __shfl_xor(mx, 8));
          float e0v = __expf(v0 - mx), e1v = __expf(v1 - mx);
          float sm = e0v + e1v;
          sm += __shfl_xor(sm, 1); sm += __shfl_xor(sm, 2);
          sm += __shfl_xor(sm, 4); sm += __shfl_xor(sm, 8);
          float iv = 1.f / sm;
          Ph[q * 32 + ln]      = (f16)(e0v * iv * p0);
          Ph[q * 32 + 16 + ln] = (f16)(e1v * iv * p1);
        }
      }
      // PV (wave-local RAW on Ph; compiler inserts the lgkmcnt wait)
      f16x8 pa[2], vb[2];
#pragma unroll
      for (int mt = 0; mt < 2; ++mt)
        pa[mt] = *(const f16x8*)&Ph[(mt * 16 + ln) * 32 + g * 8];
#pragma unroll
      for (int nt = 0; nt < 2; ++nt)
        vb[nt] = *(const f16x8*)&Vt[((2 * h + nt) * 16 + ln) * 40 + g * 8];
      f32x4 u[2][2] = {};
#pragma unroll
      for (int mt = 0; mt < 2; ++mt)
#pragma unroll
        for (int nt = 0; nt < 2; ++nt) u[mt][nt] = MFMA16(pa[mt], vb[nt], u[mt][nt]);
#pragma unroll
      for (int mt = 0; mt < 2; ++mt)
#pragma unroll
        for (int nt = 0; nt < 2; ++nt)
#pragma unroll
          for (int i = 0; i < 4; ++i)
            hEh[(mt * 16 + 4 * g + i) * 136 + h * 32 + nt * 16 + ln] = (f16)u[mt][nt][i];
    }
    __syncthreads();   // B2: upd complete

    // ---- WO: hE += upd @ wo ----
    {
      f32x4 acc[2][2] = {};
      mfma_block8(hEh, 136, PO, wv, wv + 4, acc, ln, g, lane);
#pragma unroll
      for (int nts = 0; nts < 2; ++nts) {
        int c = (wv + nts * 4) * 16 + ln;
#pragma unroll
        for (int mt = 0; mt < 2; ++mt)
#pragma unroll
          for (int i = 0; i < 4; ++i) {
            int r = mt * 16 + 4 * g + i;
            if (r < KNB) hE[r][c] += acc[mt][nts][i];
          }
      }
    }
    __syncthreads();   // B3
    layer_norm_cvt(hE, hEh, l1g + l * HID, l1b + l * HID, 1.f, tid);
    __syncthreads();   // B4

    // ---- FF: 2 chunks of 256 hidden; hid aliases Qh+Kh ----
    {
      f16x8 aff[2][4];
#pragma unroll
      for (int mt = 0; mt < 2; ++mt)
#pragma unroll
        for (int ks = 0; ks < 4; ++ks)
          aff[mt][ks] = *(const f16x8*)&hEh[(mt * 16 + ln) * 136 + ks * 32 + g * 8];
      f32x4 ff[2][2] = {};
      const float* b1 = f1b + l * NFF;
#pragma unroll
      for (int ch = 0; ch < 2; ++ch) {
        f32x4 h1[2][4] = {};
#pragma unroll
        for (int ks = 0; ks < 4; ++ks)
#pragma unroll
          for (int t = 0; t < 4; ++t) {
            f16x8 bv = P1[(ks * 32 + ch * 16 + t * 4 + wv) * 64 + lane];
            h1[0][t] = MFMA16(aff[0][ks], bv, h1[0][t]);
            h1[1][t] = MFMA16(aff[1][ks], bv, h1[1][t]);
          }
#pragma unroll
        for (int t = 0; t < 4; ++t) {
          int ntl = t * 4 + wv;
          float b1v = b1[ch * 256 + ntl * 16 + ln];
#pragma unroll
          for (int mt = 0; mt < 2; ++mt)
#pragma unroll
            for (int i = 0; i < 4; ++i)
              hid[(mt * 16 + 4 * g + i) * 264 + ntl * 16 + ln] =
                  (f16)fmaxf(h1[mt][t][i] + b1v, 0.f);
        }
        __syncthreads();   // hid chunk ready
#pragma unroll
        for (int k2 = 0; k2 < 8; ++k2) {
          f16x8 a0 = *(const f16x8*)&hid[ln * 264 + k2 * 32 + g * 8];
          f16x8 a1 = *(const f16x8*)&hid[(16 + ln) * 264 + k2 * 32 + g * 8];
          f16x8 w0 = P2[((ch * 8 + k2) * 8 + wv) * 64 + lane];
          f16x8 w1 = P2[((ch * 8 + k2) * 8 + wv + 4) * 64 + lane];
          ff[0][0] = MFMA16(a0, w0, ff[0][0]);
          ff[0][1] = MFMA16(a0, w1, ff[0][1]);
          ff[1][0] = MFMA16(a1, w0, ff[1][0]);
          ff[1][1] = MFMA16(a1, w1, ff[1][1]);
        }
        if (ch == 0) __syncthreads();   // hid free for chunk 1
      }
      const float* b2 = f2b + l * HID;
#pragma unroll
      for (int nts = 0; nts < 2; ++nts) {
        int c = (wv + nts * 4) * 16 + ln;
        float b2v = b2[c];
#pragma unroll
        for (int mt = 0; mt < 2; ++mt)
#pragma unroll
          for (int i = 0; i < 4; ++i) {
            int r = mt * 16 + 4 * g + i;
            if (r < KNB) hE[r][c] += ff[mt][nts][i] + b2v;
          }
      }
    }
    __syncthreads();   // B8
    layer_norm_cvt(hE, hEh, l2g + l * HID, l2b + l * HID, mrow, tid);
    __syncthreads();   // B9
  }

  // ---- h_out = hEh @ Wout + bout ----
  {
    float* gO = gOUT + (size_t)ebase * NOUT;
    f16x8 af[2][4];
#pragma unroll
    for (int mt = 0; mt < 2; ++mt)
#pragma unroll
      for (int ks = 0; ks < 4; ++ks)
        af[mt][ks] = *(const f16x8*)&hEh[(mt * 16 + ln) * 136 + ks * 32 + g * 8];
    const f16x8* PW = (const f16x8*)(P + PK_WOUT);
#pragma unroll
    for (int mt = 0; mt < 2; ++mt) {
      for (int nt = wv; nt < 25; nt += 4) {
        f32x4 acc = {};
#pragma unroll
        for (int ks = 0; ks < 4; ++ks) {
          f16x8 bv = PW[(ks * 25 + nt) * 64 + lane];
          acc = MFMA16(af[mt][ks], bv, acc);
        }
        int c = nt * 16 + ln;
        float bo = bout[c];
#pragma unroll
        for (int i = 0; i < 4; ++i) {
          int r = mt * 16 + 4 * g + i;
          if (r < KNB) gO[(size_t)r * NOUT + c] = acc[i] + bo;
        }
      }
    }
  }
}

// ---- merge_duplicate_edges ----
__global__ void k_buildT(const int* __restrict__ Eix, int* __restrict__ T) {
  int idx = blockIdx.x * 256 + threadIdx.x;
  if (idx < 2 * NB * KNB) {
    int b = idx / (NB * KNB);
    int rem = idx % (NB * KNB);
    int i = rem / KNB, k = rem % KNB;
    int j = Eix[idx];
    atomicMax(&T[(b * NB + i) * NB + j], k + 1);
  }
}
__global__ void k_merge(const float* __restrict__ HO, const int* __restrict__ Eix,
                        const int* __restrict__ T, float* __restrict__ out) {
  int gid = blockIdx.x * 256 + threadIdx.x;
  if (gid >= 2 * NB * KNB * (NOUT / 4)) return;
  int c4 = gid % (NOUT / 4);
  int bnk = gid / (NOUT / 4);
  int b = bnk / (NB * KNB);
  int n = (bnk / KNB) % NB;
  int j = Eix[bnk];
  int kp = T[(b * NB + j) * NB + n];
  float4 a = ((const float4*)HO)[(size_t)bnk * (NOUT / 4) + c4];
  float4 rv = make_float4(0.f, 0.f, 0.f, 0.f);
  if (kp > 0) rv = ((const float4*)HO)[(size_t)((b * NB + j) * KNB + (kp - 1)) * (NOUT / 4) + c4];
  ((float4*)out)[gid] = make_float4(0.5f * (a.x + rv.x), 0.5f * (a.y + rv.y),
                                    0.5f * (a.z + rv.z), 0.5f * (a.w + rv.w));
}

extern "C" void kernel_launch(void* const* d_in, const int* in_sizes, int n_in,
                              void* d_out, int out_size, void* d_ws, size_t ws_size,
                              hipStream_t stream) {
  const float* V   = (const float*)d_in[0];
  const float* E   = (const float*)d_in[1];
  const float* xmk = (const float*)d_in[2];
  const int*   Eix = (const int*)d_in[3];
  const float* Wv  = (const float*)d_in[4];
  const float* bv  = (const float*)d_in[5];
  const float* We  = (const float*)d_in[6];
  const float* be  = (const float*)d_in[7];
  const float* WQ  = (const float*)d_in[8];
  const float* WK  = (const float*)d_in[9];
  const float* WVp = (const float*)d_in[10];
  const float* WO  = (const float*)d_in[11];
  const float* l1g = (const float*)d_in[12];
  const float* l1b = (const float*)d_in[13];
  const float* l2g = (const float*)d_in[14];
  const float* l2b = (const float*)d_in[15];
  const float* f1w = (const float*)d_in[16];
  const float* f1b = (const float*)d_in[17];
  const float* f2w = (const float*)d_in[18];
  const float* f2b = (const float*)d_in[19];
  const float* Wou = (const float*)d_in[20];
  const float* bou = (const float*)d_in[21];

  // ws (floats): HO 12,288,000 | tbl 1,572,864 | hV 131,072 | P (f16) 657,408
  // T (2 MB) aliases tbl (tbl dead after k_main; T cleared in k_prep, built before k_main,
  // read only by k_merge after k_main — and tbl is not written after k_prep). Note: T
  // aliasing tbl is safe because buildT/merge only touch T = first 1 MB of tbl? NO —
  // keep them separate to be safe: T gets its own region after P.
  float* HO  = (float*)d_ws;
  float* tbl = HO + 12288000ull;
  float* hV  = tbl + 1572864ull;
  f16*   P   = (f16*)(hV + 131072ull);
  int*   T   = (int*)(P + PK_TOTAL + 256);   // 524,288 ints, own region

  k_hv<<<512, 256, 0, stream>>>(V, Wv, bv, hV);
  k_prep<<<10760, 256, 0, stream>>>(hV, WK, WVp, tbl, We, WQ, WO, f1w, f2w, Wou, P, T);
  k_buildT<<<120, 256, 0, stream>>>(Eix, T);
  k_main<<<1024, 256, 0, stream>>>(E, Eix, xmk, be, l1g, l1b, l2g, l2b,
                                   f1b, f2b, bou, P, tbl, HO);
  k_merge<<<12000, 256, 0, stream>>>(HO, Eix, T, (float*)d_out);
}